// Round 1
// baseline (1253.600 us; speedup 1.0000x reference)
//
#include <hip/hip_runtime.h>

// CappedMean: out[b,d] = mean(x[b, 0:N[b], d]) for x:(B=2048, L=512, D=256) f32.
// Memory-bound: read ~sum(N)*D*4 bytes once, coalesced float4, one block per b.

constexpr int LL = 512;   // L
constexpr int DD = 256;   // D
constexpr int D4 = DD / 4; // 64 float4 per row
constexpr int LWAVES = 4;  // 4 waves per block, each handles l % 4 == wave_id

__global__ __launch_bounds__(256) void capped_mean_kernel(
    const float* __restrict__ x,
    const int* __restrict__ N,
    float* __restrict__ out) {
  const int b    = blockIdx.x;
  const int tid  = threadIdx.x;
  const int d4   = tid & (D4 - 1);  // float4 column within row (0..63)
  const int lrow = tid >> 6;        // which wave: row offset 0..3

  const int n = N[b];

  const float4* __restrict__ x4 =
      reinterpret_cast<const float4*>(x + (size_t)b * LL * DD);

  float4 acc = make_float4(0.f, 0.f, 0.f, 0.f);

  // Stream rows lrow, lrow+4, ... < n. 64 lanes x 16B = 1 KiB coalesced per
  // wave-instruction. Unroll so multiple global_load_dwordx4 stay in flight.
  #pragma unroll 4
  for (int l = lrow; l < n; l += LWAVES) {
    float4 v = x4[(size_t)l * D4 + d4];
    acc.x += v.x;
    acc.y += v.y;
    acc.z += v.z;
    acc.w += v.w;
  }

  // Cross-wave reduction: 4 partial sums per float4 column.
  __shared__ float4 red[LWAVES][D4];
  red[lrow][d4] = acc;
  __syncthreads();

  if (tid < D4) {
    float4 a0 = red[0][tid];
    float4 a1 = red[1][tid];
    float4 a2 = red[2][tid];
    float4 a3 = red[3][tid];
    const float inv = 1.0f / (float)n;
    float4 r;
    r.x = (a0.x + a1.x + a2.x + a3.x) * inv;
    r.y = (a0.y + a1.y + a2.y + a3.y) * inv;
    r.z = (a0.z + a1.z + a2.z + a3.z) * inv;
    r.w = (a0.w + a1.w + a2.w + a3.w) * inv;
    reinterpret_cast<float4*>(out)[(size_t)b * D4 + tid] = r;
  }
}

extern "C" void kernel_launch(void* const* d_in, const int* in_sizes, int n_in,
                              void* d_out, int out_size, void* d_ws, size_t ws_size,
                              hipStream_t stream) {
  const float* x = (const float*)d_in[0];
  const int*   N = (const int*)d_in[1];
  float*     out = (float*)d_out;

  const int B = in_sizes[1];  // 2048 (element count of N)

  dim3 grid(B);
  dim3 block(LWAVES * 64);
  hipLaunchKernelGGL(capped_mean_kernel, grid, block, 0, stream, x, N, out);
}

// Round 2
// 1240.852 us; speedup vs baseline: 1.0103x; 1.0103x over previous
//
#include <hip/hip_runtime.h>

// CappedMean: out[b,d] = mean(x[b, 0:N[b], d]), x:(B=2048, L=512, D=256) f32.
// Round 2: fixed 64-row chunks for load balance. Kernel 1 writes partial sums
// [B, 8, D] to ws (deterministic, no atomics); kernel 2 reduces live chunks,
// scales by 1/N, writes out. HBM floor ~535 MB read + 2 MB write.

constexpr int LL = 512;          // L
constexpr int DD = 256;          // D
constexpr int D4 = DD / 4;       // 64 float4 per row
constexpr int CH = 64;           // rows per chunk
constexpr int NCHUNK = LL / CH;  // 8 chunks per batch

__global__ __launch_bounds__(256) void capped_mean_partial(
    const float* __restrict__ x,
    const int* __restrict__ N,
    float4* __restrict__ part) {  // [B, NCHUNK, D4] float4
  const int b = blockIdx.x;
  const int t = blockIdx.y;
  const int n = N[b];
  const int l0 = t * CH;
  if (l0 >= n) return;  // block-uniform early exit (chunk beyond this batch's length)

  const int lend = (l0 + CH < n) ? (l0 + CH) : n;
  const int tid = threadIdx.x;
  const int d4  = tid & (D4 - 1);  // float4 column 0..63
  const int wl  = tid >> 6;        // wave id 0..3 -> row offset within chunk

  const float4* __restrict__ x4 =
      reinterpret_cast<const float4*>(x + (size_t)b * LL * DD);

  float4 acc = make_float4(0.f, 0.f, 0.f, 0.f);
  // Up to 16 iterations; 64 lanes x 16B coalesced per wave-instruction.
  #pragma unroll 4
  for (int l = l0 + wl; l < lend; l += 4) {
    float4 v = x4[(size_t)l * D4 + d4];
    acc.x += v.x;
    acc.y += v.y;
    acc.z += v.z;
    acc.w += v.w;
  }

  __shared__ float4 red[4][D4];
  red[wl][d4] = acc;
  __syncthreads();

  if (tid < D4) {
    float4 a0 = red[0][tid];
    float4 a1 = red[1][tid];
    float4 a2 = red[2][tid];
    float4 a3 = red[3][tid];
    float4 r;
    r.x = a0.x + a1.x + a2.x + a3.x;
    r.y = a0.y + a1.y + a2.y + a3.y;
    r.z = a0.z + a1.z + a2.z + a3.z;
    r.w = a0.w + a1.w + a2.w + a3.w;
    part[((size_t)b * NCHUNK + t) * D4 + tid] = r;
  }
}

__global__ __launch_bounds__(64) void capped_mean_final(
    const float4* __restrict__ part,  // [B, NCHUNK, D4]
    const int* __restrict__ N,
    float4* __restrict__ out) {       // [B, D4]
  const int b   = blockIdx.x;
  const int tid = threadIdx.x;  // 0..63
  const int n   = N[b];
  const int nt  = (n + CH - 1) / CH;  // live chunks (>=1 since n>=1)

  float4 s = make_float4(0.f, 0.f, 0.f, 0.f);
  for (int t = 0; t < nt; ++t) {
    float4 v = part[((size_t)b * NCHUNK + t) * D4 + tid];
    s.x += v.x;
    s.y += v.y;
    s.z += v.z;
    s.w += v.w;
  }
  const float inv = 1.0f / (float)n;
  float4 r;
  r.x = s.x * inv;
  r.y = s.y * inv;
  r.z = s.z * inv;
  r.w = s.w * inv;
  out[(size_t)b * D4 + tid] = r;
}

extern "C" void kernel_launch(void* const* d_in, const int* in_sizes, int n_in,
                              void* d_out, int out_size, void* d_ws, size_t ws_size,
                              hipStream_t stream) {
  const float* x = (const float*)d_in[0];
  const int*   N = (const int*)d_in[1];
  float*     out = (float*)d_out;
  float4*   part = (float4*)d_ws;  // needs B*NCHUNK*D4*16 = 16 MB

  const int B = in_sizes[1];  // 2048

  dim3 grid1(B, NCHUNK);
  hipLaunchKernelGGL(capped_mean_partial, grid1, dim3(256), 0, stream, x, N, part);

  dim3 grid2(B);
  hipLaunchKernelGGL(capped_mean_final, grid2, dim3(64), 0, stream,
                     (const float4*)part, N, (float4*)out);
}